// Round 5
// baseline (682.401 us; speedup 1.0000x reference)
//
#include <hip/hip_runtime.h>

// out[t] += msg[e], t = edge_index[1][e].  msg:(E,32)f32, edge_index:(2,E)i32,
// out:(N,32)f32.  E=1.6M, N=100K.
// Strategy: coarse counting-sort by bucket = tgt>>7 (128 nodes/bucket), then
// per-bucket LDS-accumulated reduce. No global f32 atomics, no per-node sort.

#define FEAT    32
#define NPB     128          // nodes per bucket (pow2; LDS acc = 128*32*4 = 16 KB)
#define CHUNK   16384        // edges per binning block
#define SCAN_BS 1024
#define PART_BS 256
#define MAXB    1024         // LDS capacity for bucket counters

// ---- phase 1: per-chunk bucket histogram, written bucket-major --------------
__global__ void bucket_hist_kernel(const int* __restrict__ tgt, int* __restrict__ hist,
                                   int E, int nblk, int NB) {
    __shared__ int h[MAXB];
    for (int k = threadIdx.x; k < NB; k += blockDim.x) h[k] = 0;
    __syncthreads();
    int base = blockIdx.x * CHUNK;
    int end = min(base + CHUNK, E);
    for (int i = base + threadIdx.x; i < end; i += blockDim.x)
        atomicAdd(&h[tgt[i] >> 7], 1);                 // LDS atomic
    __syncthreads();
    for (int k = threadIdx.x; k < NB; k += blockDim.x)
        hist[k * nblk + blockIdx.x] = h[k];            // bucket-major layout
}

// ---- phase 2: hierarchical exclusive scan over M = NB*nblk entries ----------
__global__ void scan_block_kernel(const int* __restrict__ in, int* __restrict__ off,
                                  int* __restrict__ psum, int M) {
    __shared__ int s[SCAN_BS];
    int i = blockIdx.x * SCAN_BS + threadIdx.x;
    s[threadIdx.x] = (i < M) ? in[i] : 0;
    __syncthreads();
    for (int d = 1; d < SCAN_BS; d <<= 1) {
        int t = (threadIdx.x >= d) ? s[threadIdx.x - d] : 0;
        __syncthreads();
        s[threadIdx.x] += t;
        __syncthreads();
    }
    if (i < M) off[i + 1] = s[threadIdx.x];
    if (threadIdx.x == SCAN_BS - 1) psum[blockIdx.x] = s[SCAN_BS - 1];
}

__global__ void scan_partials_kernel(int* __restrict__ psum, int nb) {
    __shared__ int s[PART_BS];
    int run = 0;
    for (int base = 0; base < nb; base += PART_BS) {
        int i = base + threadIdx.x;
        int v = (i < nb) ? psum[i] : 0;
        s[threadIdx.x] = v;
        __syncthreads();
        for (int d = 1; d < PART_BS; d <<= 1) {
            int t = (threadIdx.x >= d) ? s[threadIdx.x - d] : 0;
            __syncthreads();
            s[threadIdx.x] += t;
            __syncthreads();
        }
        if (i < nb) psum[i] = run + s[threadIdx.x] - v;    // exclusive
        run += s[PART_BS - 1];
        __syncthreads();
    }
}

__global__ void finalize_offsets_kernel(int* __restrict__ off, const int* __restrict__ psum,
                                        int M) {
    int i = blockIdx.x * SCAN_BS + threadIdx.x;
    if (i == 0) off[0] = 0;
    if (i < M) off[i + 1] += psum[blockIdx.x];
}

// ---- phase 3: scatter packed (local<<24 | edge) into bucket-sorted order ----
__global__ void scatter_pack_kernel(const int* __restrict__ tgt, const int* __restrict__ off,
                                    int* __restrict__ packed, int E, int nblk, int NB) {
    __shared__ int cur[MAXB];
    for (int k = threadIdx.x; k < NB; k += blockDim.x)
        cur[k] = off[k * nblk + blockIdx.x];           // this block's base per bucket
    __syncthreads();
    int base = blockIdx.x * CHUNK;
    int end = min(base + CHUNK, E);
    for (int i = base + threadIdx.x; i < end; i += blockDim.x) {
        int t = tgt[i];
        int pos = atomicAdd(&cur[t >> 7], 1);          // LDS cursor
        packed[pos] = ((t & (NPB - 1)) << 24) | i;     // e < 2^24
    }
}

// ---- phase 4: per-bucket reduce in LDS, single coalesced out write ----------
__global__ void bucket_reduce_kernel(const float* __restrict__ msg,
                                     const int* __restrict__ packed,
                                     const int* __restrict__ off,
                                     float* __restrict__ out,
                                     int E, int nblk, int NB, int N) {
    __shared__ float acc[NPB * FEAT];                  // 16 KB
    for (int i = threadIdx.x; i < NPB * FEAT; i += blockDim.x) acc[i] = 0.f;
    __syncthreads();
    int k = blockIdx.x;
    int s0 = off[k * nblk];
    int s1 = (k + 1 < NB) ? off[(k + 1) * nblk] : E;
    int slot = threadIdx.x >> 5;                       // 8 edge slots
    int f = threadIdx.x & 31;                          // 32 feats
    for (int j = s0; j < s1; j += 32) {                // 8 slots x unroll 4
#pragma unroll
        for (int u = 0; u < 4; ++u) {
            int jj = j + u * 8 + slot;
            int p = packed[jj < s1 ? jj : s1 - 1];     // clamped: no serial tail
            float m = msg[(size_t)(p & 0xFFFFFF) * FEAT + f];  // 128 B coalesced row
            if (jj < s1) atomicAdd(&acc[(p >> 24) * FEAT + f], m);  // ds_add_f32
        }
    }
    __syncthreads();
    int nodebase = k * NPB;
    for (int i = threadIdx.x; i < NPB * FEAT; i += blockDim.x) {
        int l = i >> 5;
        if (nodebase + l < N)
            out[(size_t)(nodebase + l) * FEAT + (i & 31)] = acc[i];  // written once
    }
}

extern "C" void kernel_launch(void* const* d_in, const int* in_sizes, int n_in,
                              void* d_out, int out_size, void* d_ws, size_t ws_size,
                              hipStream_t stream) {
    const float* msg = (const float*)d_in[0];
    const int* edge_index = (const int*)d_in[1];
    int E = in_sizes[0] / FEAT;                        // 1,600,000
    int N = out_size / FEAT;                           // 100,000
    const int* tgt = edge_index + E;                   // row 1 of (2,E)

    int NB   = (N + NPB - 1) / NPB;                    // 782 buckets
    int nblk = (E + CHUNK - 1) / CHUNK;                // 98 binning blocks
    int M    = NB * nblk;                              // 76,636
    int nb2  = (M + SCAN_BS - 1) / SCAN_BS;            // 75 scan blocks

    // ws (ints): hist[M] | off[M+1] | psum[nb2] | packed[E]  ~= 7.0 MB
    int* hist   = (int*)d_ws;
    int* off    = hist + M;
    int* psum   = off + M + 1;
    int* packed = psum + nb2;

    bucket_hist_kernel<<<nblk, 256, 0, stream>>>(tgt, hist, E, nblk, NB);
    scan_block_kernel<<<nb2, SCAN_BS, 0, stream>>>(hist, off, psum, M);
    scan_partials_kernel<<<1, PART_BS, 0, stream>>>(psum, nb2);
    finalize_offsets_kernel<<<nb2, SCAN_BS, 0, stream>>>(off, psum, M);
    scatter_pack_kernel<<<nblk, 256, 0, stream>>>(tgt, off, packed, E, nblk, NB);
    bucket_reduce_kernel<<<NB, 256, 0, stream>>>(msg, packed, off, (float*)d_out,
                                                 E, nblk, NB, N);
}

// Round 6
// 595.155 us; speedup vs baseline: 1.1466x; 1.1466x over previous
//
#include <hip/hip_runtime.h>

// out[t] += msg[e], t = edge_index[1][e].  msg:(E,32)f32, edge_index:(2,E)i32,
// out:(N,32)f32.  E=1.6M, N=100K.
// Coarse counting-sort by bucket = tgt>>7 (128 nodes/bucket), then per-bucket
// LDS-accumulated reduce with deep memory-level parallelism.

#define FEAT    32
#define NPB     128          // nodes per bucket (LDS acc = 128*32*4 = 16 KB)
#define CHUNK   16384        // edges per binning block
#define SCAN_BS 1024
#define PART_BS 256
#define MAXB    1024         // LDS capacity for bucket counters
#define RU      16           // reduce unroll (rows in flight per slot)

// ---- phase 1: per-chunk bucket histogram, written bucket-major --------------
__global__ void bucket_hist_kernel(const int* __restrict__ tgt, int* __restrict__ hist,
                                   int E, int nblk, int NB) {
    __shared__ int h[MAXB];
    for (int k = threadIdx.x; k < NB; k += blockDim.x) h[k] = 0;
    __syncthreads();
    int base = blockIdx.x * CHUNK;
    int end = min(base + CHUNK, E);
    for (int i = base + threadIdx.x; i < end; i += blockDim.x)
        atomicAdd(&h[tgt[i] >> 7], 1);                 // LDS atomic
    __syncthreads();
    for (int k = threadIdx.x; k < NB; k += blockDim.x)
        hist[k * nblk + blockIdx.x] = h[k];            // bucket-major layout
}

// ---- phase 2: hierarchical exclusive scan over M = NB*nblk entries ----------
__global__ void scan_block_kernel(const int* __restrict__ in, int* __restrict__ off,
                                  int* __restrict__ psum, int M) {
    __shared__ int s[SCAN_BS];
    int i = blockIdx.x * SCAN_BS + threadIdx.x;
    s[threadIdx.x] = (i < M) ? in[i] : 0;
    __syncthreads();
    for (int d = 1; d < SCAN_BS; d <<= 1) {
        int t = (threadIdx.x >= d) ? s[threadIdx.x - d] : 0;
        __syncthreads();
        s[threadIdx.x] += t;
        __syncthreads();
    }
    if (i < M) off[i + 1] = s[threadIdx.x];
    if (threadIdx.x == SCAN_BS - 1) psum[blockIdx.x] = s[SCAN_BS - 1];
}

__global__ void scan_partials_kernel(int* __restrict__ psum, int nb) {
    __shared__ int s[PART_BS];
    int run = 0;
    for (int base = 0; base < nb; base += PART_BS) {
        int i = base + threadIdx.x;
        int v = (i < nb) ? psum[i] : 0;
        s[threadIdx.x] = v;
        __syncthreads();
        for (int d = 1; d < PART_BS; d <<= 1) {
            int t = (threadIdx.x >= d) ? s[threadIdx.x - d] : 0;
            __syncthreads();
            s[threadIdx.x] += t;
            __syncthreads();
        }
        if (i < nb) psum[i] = run + s[threadIdx.x] - v;    // exclusive
        run += s[PART_BS - 1];
        __syncthreads();
    }
}

__global__ void finalize_offsets_kernel(int* __restrict__ off, const int* __restrict__ psum,
                                        int M) {
    int i = blockIdx.x * SCAN_BS + threadIdx.x;
    if (i == 0) off[0] = 0;
    if (i < M) off[i + 1] += psum[blockIdx.x];
}

// ---- phase 3: scatter packed (local<<24 | edge) into bucket-sorted order ----
__global__ void scatter_pack_kernel(const int* __restrict__ tgt, const int* __restrict__ off,
                                    int* __restrict__ packed, int E, int nblk, int NB) {
    __shared__ int cur[MAXB];
    for (int k = threadIdx.x; k < NB; k += blockDim.x)
        cur[k] = off[k * nblk + blockIdx.x];           // this block's base per bucket
    __syncthreads();
    int base = blockIdx.x * CHUNK;
    int end = min(base + CHUNK, E);
    for (int i = base + threadIdx.x; i < end; i += blockDim.x) {
        int t = tgt[i];
        int pos = atomicAdd(&cur[t >> 7], 1);          // LDS cursor
        packed[pos] = ((t & (NPB - 1)) << 24) | i;     // e < 2^24
    }
}

// ---- phase 4: per-bucket reduce in LDS; 16 slots x 32 feats, 16-deep MLP ----
// Three separated phases per 256-edge tile (all packed loads -> all msg loads
// -> all LDS atomics) so 256 independent 128 B rows are in flight per block.
__global__ __launch_bounds__(512, 6)
void bucket_reduce_kernel(const float* __restrict__ msg,
                          const int* __restrict__ packed,
                          const int* __restrict__ off,
                          float* __restrict__ out,
                          int E, int nblk, int NB, int N) {
    __shared__ float acc[NPB * FEAT];                  // 16 KB
    for (int i = threadIdx.x; i < NPB * FEAT; i += blockDim.x) acc[i] = 0.f;
    __syncthreads();
    int k = blockIdx.x;
    int s0 = off[k * nblk];
    int s1 = (k + 1 < NB) ? off[(k + 1) * nblk] : E;
    int slot = threadIdx.x >> 5;                       // 16 edge slots
    int f = threadIdx.x & 31;                          // 32 feats (conflict-free LDS)
    for (int j = s0; j < s1; j += 16 * RU) {           // 256-edge tile
        int p[RU];
        float m[RU];
#pragma unroll
        for (int u = 0; u < RU; ++u) {                 // phase A: 16 packed words
            int jj = j + u * 16 + slot;
            p[u] = packed[jj < s1 ? jj : s1 - 1];      // clamped: no tail branch
        }
#pragma unroll
        for (int u = 0; u < RU; ++u)                   // phase B: 16 indep rows
            m[u] = msg[(size_t)(p[u] & 0xFFFFFF) * FEAT + f];
#pragma unroll
        for (int u = 0; u < RU; ++u) {                 // phase C: LDS accumulate
            int jj = j + u * 16 + slot;
            if (jj < s1)
                atomicAdd(&acc[(p[u] >> 24) * FEAT + f], m[u]);  // ds_add_f32, 2-way
        }
    }
    __syncthreads();
    int nodebase = k * NPB;
    for (int i = threadIdx.x; i < NPB * FEAT; i += blockDim.x) {
        int l = i >> 5;
        if (nodebase + l < N)
            out[(size_t)(nodebase + l) * FEAT + (i & 31)] = acc[i];  // written once
    }
}

extern "C" void kernel_launch(void* const* d_in, const int* in_sizes, int n_in,
                              void* d_out, int out_size, void* d_ws, size_t ws_size,
                              hipStream_t stream) {
    const float* msg = (const float*)d_in[0];
    const int* edge_index = (const int*)d_in[1];
    int E = in_sizes[0] / FEAT;                        // 1,600,000
    int N = out_size / FEAT;                           // 100,000
    const int* tgt = edge_index + E;                   // row 1 of (2,E)

    int NB   = (N + NPB - 1) / NPB;                    // 782 buckets
    int nblk = (E + CHUNK - 1) / CHUNK;                // 98 binning blocks
    int M    = NB * nblk;                              // 76,636
    int nb2  = (M + SCAN_BS - 1) / SCAN_BS;            // 75 scan blocks

    // ws (ints): hist[M] | off[M+1] | psum[nb2] | packed[E]  ~= 7.0 MB
    int* hist   = (int*)d_ws;
    int* off    = hist + M;
    int* psum   = off + M + 1;
    int* packed = psum + nb2;

    bucket_hist_kernel<<<nblk, 512, 0, stream>>>(tgt, hist, E, nblk, NB);
    scan_block_kernel<<<nb2, SCAN_BS, 0, stream>>>(hist, off, psum, M);
    scan_partials_kernel<<<1, PART_BS, 0, stream>>>(psum, nb2);
    finalize_offsets_kernel<<<nb2, SCAN_BS, 0, stream>>>(off, psum, M);
    scatter_pack_kernel<<<nblk, 512, 0, stream>>>(tgt, off, packed, E, nblk, NB);
    bucket_reduce_kernel<<<NB, 512, 0, stream>>>(msg, packed, off, (float*)d_out,
                                                 E, nblk, NB, N);
}

// Round 8
// 574.740 us; speedup vs baseline: 1.1873x; 1.0355x over previous
//
#include <hip/hip_runtime.h>

// out[t] += msg[e], t = edge_index[1][e].  msg:(E,32)f32, edge_index:(2,E)i32,
// out:(N,32)f32.  E=1.6M, N=100K.
// Coarse counting-sort by bucket = tgt>>6 (64 nodes/bucket), then per-bucket
// LDS-accumulated reduce with inline-asm-forced 16-deep global loads.

#define FEAT    32
#define NPB     64           // nodes per bucket (LDS acc = 64*32*4 = 8 KB)
#define CHUNK   32768        // edges per binning block
#define SCAN_BS 1024
#define PART_BS 256
#define MAXB    2048         // LDS capacity for bucket counters
#define RU      16           // reduce unroll (rows in flight per slot)
#define NSLOT   16           // edge slots per block (512 thr / 32 feats)

// ---- phase 1: per-chunk bucket histogram, written bucket-major --------------
__global__ void bucket_hist_kernel(const int* __restrict__ tgt, int* __restrict__ hist,
                                   int E, int nblk, int NB) {
    __shared__ int h[MAXB];
    for (int k = threadIdx.x; k < NB; k += blockDim.x) h[k] = 0;
    __syncthreads();
    int base = blockIdx.x * CHUNK;
    int end = min(base + CHUNK, E);
    for (int i = base + threadIdx.x; i < end; i += blockDim.x)
        atomicAdd(&h[tgt[i] >> 6], 1);                 // LDS atomic
    __syncthreads();
    for (int k = threadIdx.x; k < NB; k += blockDim.x)
        hist[k * nblk + blockIdx.x] = h[k];            // bucket-major layout
}

// ---- phase 2: hierarchical exclusive scan over M = NB*nblk entries ----------
__global__ void scan_block_kernel(const int* __restrict__ in, int* __restrict__ off,
                                  int* __restrict__ psum, int M) {
    __shared__ int s[SCAN_BS];
    int i = blockIdx.x * SCAN_BS + threadIdx.x;
    s[threadIdx.x] = (i < M) ? in[i] : 0;
    __syncthreads();
    for (int d = 1; d < SCAN_BS; d <<= 1) {
        int t = (threadIdx.x >= d) ? s[threadIdx.x - d] : 0;
        __syncthreads();
        s[threadIdx.x] += t;
        __syncthreads();
    }
    if (i < M) off[i + 1] = s[threadIdx.x];
    if (threadIdx.x == SCAN_BS - 1) psum[blockIdx.x] = s[SCAN_BS - 1];
}

__global__ void scan_partials_kernel(int* __restrict__ psum, int nb) {
    __shared__ int s[PART_BS];
    int run = 0;
    for (int base = 0; base < nb; base += PART_BS) {
        int i = base + threadIdx.x;
        int v = (i < nb) ? psum[i] : 0;
        s[threadIdx.x] = v;
        __syncthreads();
        for (int d = 1; d < PART_BS; d <<= 1) {
            int t = (threadIdx.x >= d) ? s[threadIdx.x - d] : 0;
            __syncthreads();
            s[threadIdx.x] += t;
            __syncthreads();
        }
        if (i < nb) psum[i] = run + s[threadIdx.x] - v;    // exclusive
        run += s[PART_BS - 1];
        __syncthreads();
    }
}

__global__ void finalize_offsets_kernel(int* __restrict__ off, const int* __restrict__ psum,
                                        int M) {
    int i = blockIdx.x * SCAN_BS + threadIdx.x;
    if (i == 0) off[0] = 0;
    if (i < M) off[i + 1] += psum[blockIdx.x];
}

// ---- phase 3: scatter packed (local<<24 | edge) into bucket-sorted order ----
__global__ void scatter_pack_kernel(const int* __restrict__ tgt, const int* __restrict__ off,
                                    int* __restrict__ packed, int E, int nblk, int NB) {
    __shared__ int cur[MAXB];
    for (int k = threadIdx.x; k < NB; k += blockDim.x)
        cur[k] = off[k * nblk + blockIdx.x];           // this block's base per bucket
    __syncthreads();
    int base = blockIdx.x * CHUNK;
    int end = min(base + CHUNK, E);
    for (int i = base + threadIdx.x; i < end; i += blockDim.x) {
        int t = tgt[i];
        int pos = atomicAdd(&cur[t >> 6], 1);          // LDS cursor
        packed[pos] = ((t & (NPB - 1)) << 24) | i;     // e < 2^24
    }
}

// ---- phase 4: per-bucket reduce; 16 slots x 32 feats; asm-forced 16-deep ----
__global__ __launch_bounds__(512, 8)                   // <=64 VGPR, 4 blocks/CU
void bucket_reduce_kernel(const float* __restrict__ msg,
                          const int* __restrict__ packed,
                          const int* __restrict__ off,
                          float* __restrict__ out,
                          int E, int nblk, int NB, int N) {
    __shared__ float acc[NPB * FEAT];                  // 8 KB
    for (int i = threadIdx.x; i < NPB * FEAT; i += blockDim.x) acc[i] = 0.f;
    __syncthreads();
    int k = blockIdx.x;
    int s0 = off[k * nblk];
    int s1 = off[(k + 1) * nblk];                      // off[M] == E for last bucket
    int slot = threadIdx.x >> 5;                       // 16 edge slots
    int f = threadIdx.x & 31;                          // 32 feats (conflict-free LDS)
    for (int j = s0; j < s1; j += NSLOT * RU) {        // 256-edge tile
        int p[RU];
        int o32[RU];
        float m[RU];
        // phase A: compiler loads of packed words (its waitcnts resolve here,
        // before any asm VMEM issues -> its vmcnt accounting stays safe)
#pragma unroll
        for (int u = 0; u < RU; ++u) {
            int jj = j + u * NSLOT + slot;
            p[u] = packed[jj < s1 ? jj : s1 - 1];      // clamped: no tail branch
        }
        // phase B1: all 16 byte-offsets (forces p waits before any asm load)
#pragma unroll
        for (int u = 0; u < RU; ++u)
            o32[u] = ((p[u] & 0xFFFFFF) << 7) + (f << 2);   // row*128 + f*4
        // phase B2: 16 independent loads, guaranteed in flight together
#pragma unroll
        for (int u = 0; u < RU; ++u)
            asm volatile("global_load_dword %0, %1, %2"
                         : "=v"(m[u]) : "v"(o32[u]), "s"(msg) : "memory");
        asm volatile("s_waitcnt vmcnt(0)" ::: "memory");
        __builtin_amdgcn_sched_barrier(0);             // rule 18: pin consumers after
        // phase C: LDS accumulate (bank = f -> conflict-free/2-way)
#pragma unroll
        for (int u = 0; u < RU; ++u) {
            int jj = j + u * NSLOT + slot;
            if (jj < s1)
                atomicAdd(&acc[(p[u] >> 24) * FEAT + f], m[u]);  // ds_add_f32
        }
    }
    __syncthreads();
    int nodebase = k * NPB;
    for (int i = threadIdx.x; i < NPB * FEAT; i += blockDim.x) {
        int l = i >> 5;
        if (nodebase + l < N)
            out[(size_t)(nodebase + l) * FEAT + (i & 31)] = acc[i];  // written once
    }
}

// ---- fallback: atomic scatter (if ws too small) -----------------------------
__global__ void scatter_add_kernel(const float4* __restrict__ msg4,
                                   const int* __restrict__ tgt,
                                   float* __restrict__ out, int num_edges) {
    int i = blockIdx.x * blockDim.x + threadIdx.x;
    if (i >= num_edges * (FEAT / 4)) return;
    int e = i >> 3, q = i & 7;
    float4 mm = msg4[i];
    int t = tgt[e];
    float* dst = out + (size_t)t * FEAT + q * 4;
    atomicAdd(dst + 0, mm.x); atomicAdd(dst + 1, mm.y);
    atomicAdd(dst + 2, mm.z); atomicAdd(dst + 3, mm.w);
}

extern "C" void kernel_launch(void* const* d_in, const int* in_sizes, int n_in,
                              void* d_out, int out_size, void* d_ws, size_t ws_size,
                              hipStream_t stream) {
    const float* msg = (const float*)d_in[0];
    const int* edge_index = (const int*)d_in[1];
    int E = in_sizes[0] / FEAT;                        // 1,600,000
    int N = out_size / FEAT;                           // 100,000
    const int* tgt = edge_index + E;                   // row 1 of (2,E)

    int NB   = (N + NPB - 1) / NPB;                    // 1563 buckets
    int nblk = (E + CHUNK - 1) / CHUNK;                // 49 binning blocks
    int M    = NB * nblk;                              // 76,587
    int nb2  = (M + SCAN_BS - 1) / SCAN_BS;            // 75 scan blocks

    // ws (ints): hist[M] | off[M+1] | psum[nb2] | packed[E]  ~= 7.0 MB
    size_t need = ((size_t)M + (M + 1) + nb2 + E) * sizeof(int);
    if (ws_size < need) {                              // safety fallback
        hipMemsetAsync(d_out, 0, (size_t)out_size * sizeof(float), stream);
        int total = E * (FEAT / 4);
        scatter_add_kernel<<<(total + 255) / 256, 256, 0, stream>>>(
            (const float4*)msg, tgt, (float*)d_out, E);
        return;
    }
    int* hist   = (int*)d_ws;
    int* off    = hist + M;
    int* psum   = off + M + 1;
    int* packed = psum + nb2;

    bucket_hist_kernel<<<nblk, 512, 0, stream>>>(tgt, hist, E, nblk, NB);
    scan_block_kernel<<<nb2, SCAN_BS, 0, stream>>>(hist, off, psum, M);
    scan_partials_kernel<<<1, PART_BS, 0, stream>>>(psum, nb2);
    finalize_offsets_kernel<<<nb2, SCAN_BS, 0, stream>>>(off, psum, M);
    scatter_pack_kernel<<<nblk, 512, 0, stream>>>(tgt, off, packed, E, nblk, NB);
    bucket_reduce_kernel<<<NB, 512, 0, stream>>>(msg, packed, off, (float*)d_out,
                                                 E, nblk, NB, N);
}